// Round 7
// baseline (178.626 us; speedup 1.0000x reference)
//
#include <hip/hip_runtime.h>
#include <hip/hip_bf16.h>

// Sizes fixed by the reference
#define B_ 16
#define H_ 2048
#define W_ 128

using f32x4  = __attribute__((ext_vector_type(4))) float;
using bf16x8 = __attribute__((ext_vector_type(8))) short;

// async global->LDS, 16B per lane. LDS dest is wave-uniform base + lane*16;
// global src is per-lane.
#define GLOAD_LDS16(g, l) __builtin_amdgcn_global_load_lds( \
    (const __attribute__((address_space(1))) unsigned int*)(g), \
    (__attribute__((address_space(3))) unsigned int*)(l), 16, 0, 0)

__device__ inline short bf16bits(float f) {
    union { __hip_bfloat16 h; short s; } u;
    u.h = __float2bfloat16(f);
    return u.s;
}

// ---------------------------------------------------------------------------
// prep: one block per 64 g-rows of one batch.
//  Xbt: fragment-major bf16, chunk ((g/16)*4+k)*64 + q*16 + r holds
//       X[(g/16)*16+r][k*32+q*8+j]  -- written straight from registers
//  XTt: PV B-operand chunks ((kt*8+nt2)*64 + q*16 + r) per g64-group holding
//       X[g64*64+kt*32+q*8+j][nt2*16+r] -- via swizzled bf16 LDS tile
//  cs[b][g] = (sum_c b1_c w2_c) * sum_w x[b,g,w]
// ---------------------------------------------------------------------------
__global__ __launch_bounds__(256) void prep(const float* __restrict__ x,
                                            const float* __restrict__ b1,
                                            const float* __restrict__ w2,
                                            short* __restrict__ Xbt,
                                            short* __restrict__ XTt,
                                            float* __restrict__ cs) {
    __shared__ short xs2[8192];   // 64 rows x 128 cols bf16, 16B-chunk XOR swizzle
    int b  = blockIdx.x >> 5;
    int g0 = (blockIdx.x & 31) * 64;
    const float* xb = x + ((size_t)b * H_ + g0) * W_;
    short* outb = Xbt + (size_t)b * H_ * W_ + (size_t)g0 * W_;
    short* outt = XTt + (size_t)b * H_ * W_ + (size_t)g0 * W_;
    int t = threadIdx.x, seg = t & 15, row_l = t >> 4;
    float Cc = 0.f;
#pragma unroll
    for (int c = 0; c < 8; ++c) Cc += b1[c] * w2[c];

#pragma unroll
    for (int it = 0; it < 4; ++it) {
        int row = it * 16 + row_l;
        const float* src = xb + (size_t)row * W_ + seg * 8;
        float4 v0 = *reinterpret_cast<const float4*>(src);
        float4 v1 = *reinterpret_cast<const float4*>(src + 4);
        bf16x8 v;
        v[0] = bf16bits(v0.x); v[1] = bf16bits(v0.y);
        v[2] = bf16bits(v0.z); v[3] = bf16bits(v0.w);
        v[4] = bf16bits(v1.x); v[5] = bf16bits(v1.y);
        v[6] = bf16bits(v1.z); v[7] = bf16bits(v1.w);
        // Xbt chunk straight from regs
        int chunk = (it * 4 + (seg >> 2)) * 64 + (seg & 3) * 16 + row_l;
        *reinterpret_cast<bf16x8*>(outb + (size_t)chunk * 8) = v;
        // row sum (16 consecutive threads share a row)
        float s = v0.x + v0.y + v0.z + v0.w + v1.x + v1.y + v1.z + v1.w;
        s += __shfl_xor(s, 1); s += __shfl_xor(s, 2);
        s += __shfl_xor(s, 4); s += __shfl_xor(s, 8);
        if (seg == 0) cs[b * H_ + g0 + row] = Cc * s;
        // swizzled LDS store for the transpose
        int c8 = seg ^ ((row >> 3) & 3);
        *reinterpret_cast<bf16x8*>(&xs2[row * 128 + c8 * 8]) = v;
    }
    __syncthreads();
#pragma unroll
    for (int it2 = 0; it2 < 4; ++it2) {
        int c = it2 * 256 + t;
        int r = c & 15, qp = (c >> 4) & 3, nt2 = (c >> 6) & 7, kt = c >> 9;
        int w = nt2 * 16 + r, g = kt * 32 + qp * 8;
        int c8p = (w >> 3) ^ ((g >> 3) & 3);   // (g+jj)>>3 constant over jj
        bf16x8 vv;
#pragma unroll
        for (int jj = 0; jj < 8; ++jj)
            vv[jj] = xs2[(g + jj) * 128 + c8p * 8 + (w & 7)];
        *reinterpret_cast<bf16x8*>(outt + (size_t)c * 8) = vv;
    }
}

// ---------------------------------------------------------------------------
// Fused: block = 64 h-rows, 4 waves.
// S phase: wave (wh=wv>>1, wg=wv&1) computes S[g: 16 (half wg)][h: 32 (half
// wh)] per 32-g tile via swapped MFMA (P born with h=lane-col, 4 consecutive
// g per lane -> one packed ds_write_b64 per hf into shared pb).
// PV phase: wave (wh=wv>>1, wlo=wv&1) owns O[32h][64w]: o[2 hf][4 n16],
// 8 PV MFMAs per tile. All staged-tile reads happen BEFORE the single
// mid-body barrier (WAR protection vs next tile's global_load_lds).
//  sweep1: per-row min/max of t = A*S + cs[g]
//  sweep2: e = exp2((t-mn)*inv), Z, O = P @ X;  out = gamma*O/Z + x
// ---------------------------------------------------------------------------
__global__ __launch_bounds__(256, 2) void fused_attn(
    const float* __restrict__ x,
    const short* __restrict__ Xbt, const short* __restrict__ XTt,
    const float* __restrict__ cs,
    const float* __restrict__ w1, const float* __restrict__ w2,
    const float* __restrict__ gamma, float* __restrict__ out) {
    __shared__ __align__(16) char stgA[2][8192];   // 32g x 128k bf16 tile
    __shared__ __align__(16) char stgV[2][8192];   // 128w x 32g bf16 tile
    __shared__ __align__(16) char pb[2][4096];     // P: 64h x 32g bf16, dbuf
    __shared__ float red_mn[2][2][2][16];          // [wh][hf][wg][r]
    __shared__ float red_mx[2][2][2][16];
    __shared__ float zred[2][2][2][16];

    float A = 0.f;
#pragma unroll
    for (int c = 0; c < 8; ++c) A += w1[c] * w2[c];

    int tid = threadIdx.x;
    int wv = tid >> 6, lane = tid & 63;
    int wh = wv >> 1, wg = wv & 1;
    int q = lane >> 4, r = lane & 15;

    // XCD swizzle: 512 blocks, XCD k gets contiguous 64-block span = 2 batches
    int bid = blockIdx.x;
    int swz = (bid & 7) * 64 + (bid >> 3);
    int b = swz >> 5, hb = swz & 31;
    int h_base = hb * 64;

    const char* xbt = (const char*)(Xbt + (size_t)b * H_ * W_);
    const char* xtt = (const char*)(XTt + (size_t)b * H_ * W_);
    const float* csb = cs + b * H_;

    // A-fragments: 2 x (16h x 128k), in regs for the whole kernel
    bf16x8 afr[2][4];
#pragma unroll
    for (int hf = 0; hf < 2; ++hf)
#pragma unroll
        for (int k = 0; k < 4; ++k)
            afr[hf][k] = *reinterpret_cast<const bf16x8*>(
                xbt + (((size_t)((h_base >> 4) + wh * 2 + hf) * 4 + k) * 64 + lane) * 16);

    // ---------------- sweep 1: per-row min / max ----------------
    float mnv[2] = {3.4e38f, 3.4e38f}, mxv[2] = {-3.4e38f, -3.4e38f};
    {
        const char* ga = xbt + wv * 2048 + lane * 16;
        char* la = stgA[0] + wv * 2048;
        GLOAD_LDS16(ga, la); GLOAD_LDS16(ga + 1024, la + 1024);
    }
    __syncthreads();
    float4 csv = *reinterpret_cast<const float4*>(csb + wg * 16 + q * 4);
    for (int t = 0; t < 64; ++t) {
        float4 csn = csv;
        if (t < 63) {
            const char* ga = xbt + (size_t)(t + 1) * 8192 + wv * 2048 + lane * 16;
            char* la = stgA[(t + 1) & 1] + wv * 2048;
            GLOAD_LDS16(ga, la); GLOAD_LDS16(ga + 1024, la + 1024);
            csn = *reinterpret_cast<const float4*>(csb + (t + 1) * 32 + wg * 16 + q * 4);
        }
        const char* sa = stgA[t & 1] + lane * 16;
        bf16x8 bfr[4];
#pragma unroll
        for (int k = 0; k < 4; ++k)
            bfr[k] = *reinterpret_cast<const bf16x8*>(sa + ((wg * 4 + k) * 64) * 16);
        f32x4 s0 = {0.f, 0.f, 0.f, 0.f}, s1 = {0.f, 0.f, 0.f, 0.f};
#pragma unroll
        for (int k = 0; k < 4; ++k) {
            s0 = __builtin_amdgcn_mfma_f32_16x16x32_bf16(bfr[k], afr[0][k], s0, 0, 0, 0);
            s1 = __builtin_amdgcn_mfma_f32_16x16x32_bf16(bfr[k], afr[1][k], s1, 0, 0, 0);
        }
#pragma unroll
        for (int reg = 0; reg < 4; ++reg) {
            float t0 = fmaf(A, s0[reg], csv[reg]);
            float t1 = fmaf(A, s1[reg], csv[reg]);
            mnv[0] = fminf(mnv[0], t0); mxv[0] = fmaxf(mxv[0], t0);
            mnv[1] = fminf(mnv[1], t1); mxv[1] = fmaxf(mxv[1], t1);
        }
        __syncthreads();
        csv = csn;
    }
#pragma unroll
    for (int hf = 0; hf < 2; ++hf) {
        mnv[hf] = fminf(mnv[hf], __shfl_xor(mnv[hf], 16));
        mnv[hf] = fminf(mnv[hf], __shfl_xor(mnv[hf], 32));
        mxv[hf] = fmaxf(mxv[hf], __shfl_xor(mxv[hf], 16));
        mxv[hf] = fmaxf(mxv[hf], __shfl_xor(mxv[hf], 32));
    }
    if (lane < 16) {
        red_mn[wh][0][wg][lane] = mnv[0]; red_mn[wh][1][wg][lane] = mnv[1];
        red_mx[wh][0][wg][lane] = mxv[0]; red_mx[wh][1][wg][lane] = mxv[1];
    }
    __syncthreads();
    const float LOG2E = 1.4426950408889634f;
    float c1[2], c0v[2], A1[2];
#pragma unroll
    for (int hf = 0; hf < 2; ++hf) {
        float mn = fminf(red_mn[wh][hf][0][r], red_mn[wh][hf][1][r]);
        float mx = fmaxf(red_mx[wh][hf][0][r], red_mx[wh][hf][1][r]);
        float inv = LOG2E / (mx - mn + 1e-8f);
        c1[hf] = inv; c0v[hf] = -mn * inv; A1[hf] = A * inv;
    }

    // ---------------- sweep 2: exp + Z + O = P @ X ----------------
    f32x4 o[2][4];
#pragma unroll
    for (int i = 0; i < 2; ++i)
#pragma unroll
        for (int j = 0; j < 4; ++j) o[i][j] = (f32x4){0.f, 0.f, 0.f, 0.f};
    float zacc[2] = {0.f, 0.f};
    {
        const char* ga = xbt + wv * 2048 + lane * 16;
        char* la = stgA[0] + wv * 2048;
        const char* gv = xtt + wv * 2048 + lane * 16;
        char* lv = stgV[0] + wv * 2048;
        GLOAD_LDS16(ga, la); GLOAD_LDS16(ga + 1024, la + 1024);
        GLOAD_LDS16(gv, lv); GLOAD_LDS16(gv + 1024, lv + 1024);
    }
    __syncthreads();
    csv = *reinterpret_cast<const float4*>(csb + wg * 16 + q * 4);
    for (int t = 0; t < 64; ++t) {
        float4 csn = csv;
        if (t < 63) {
            const char* ga = xbt + (size_t)(t + 1) * 8192 + wv * 2048 + lane * 16;
            char* la = stgA[(t + 1) & 1] + wv * 2048;
            const char* gv = xtt + (size_t)(t + 1) * 8192 + wv * 2048 + lane * 16;
            char* lv = stgV[(t + 1) & 1] + wv * 2048;
            GLOAD_LDS16(ga, la); GLOAD_LDS16(ga + 1024, la + 1024);
            GLOAD_LDS16(gv, lv); GLOAD_LDS16(gv + 1024, lv + 1024);
            csn = *reinterpret_cast<const float4*>(csb + (t + 1) * 32 + wg * 16 + q * 4);
        }
        // ALL staged-tile reads before the barrier (WAR-safe vs next GLOADs)
        const char* sa = stgA[t & 1] + lane * 16;
        bf16x8 bfr[4];
#pragma unroll
        for (int k = 0; k < 4; ++k)
            bfr[k] = *reinterpret_cast<const bf16x8*>(sa + ((wg * 4 + k) * 64) * 16);
        const char* sv = stgV[t & 1] + lane * 16;
        bf16x8 bt[4];
#pragma unroll
        for (int n = 0; n < 4; ++n)
            bt[n] = *reinterpret_cast<const bf16x8*>(sv + (((wg * 4 + n)) * 64) * 16);
        f32x4 s0 = {0.f, 0.f, 0.f, 0.f}, s1 = {0.f, 0.f, 0.f, 0.f};
#pragma unroll
        for (int k = 0; k < 4; ++k) {
            s0 = __builtin_amdgcn_mfma_f32_16x16x32_bf16(bfr[k], afr[0][k], s0, 0, 0, 0);
            s1 = __builtin_amdgcn_mfma_f32_16x16x32_bf16(bfr[k], afr[1][k], s1, 0, 0, 0);
        }
        char* pw = pb[t & 1];
#pragma unroll
        for (int hf = 0; hf < 2; ++hf) {
            f32x4 ss = hf ? s1 : s0;
            float e0 = exp2f(fmaf(ss[0], A1[hf], fmaf(csv[0], c1[hf], c0v[hf])));
            float e1 = exp2f(fmaf(ss[1], A1[hf], fmaf(csv[1], c1[hf], c0v[hf])));
            float e2 = exp2f(fmaf(ss[2], A1[hf], fmaf(csv[2], c1[hf], c0v[hf])));
            float e3 = exp2f(fmaf(ss[3], A1[hf], fmaf(csv[3], c1[hf], c0v[hf])));
            zacc[hf] += (e0 + e1) + (e2 + e3);
            unsigned d0 = (unsigned)(unsigned short)bf16bits(e0) |
                          ((unsigned)(unsigned short)bf16bits(e1) << 16);
            unsigned d1 = (unsigned)(unsigned short)bf16bits(e2) |
                          ((unsigned)(unsigned short)bf16bits(e3) << 16);
            uint2 dd; dd.x = d0; dd.y = d1;
            *reinterpret_cast<uint2*>(
                pw + (((wh * 2 + hf) * 64 + (wg * 2 + (q >> 1)) * 16 + r) * 16 + (q & 1) * 8)) = dd;
        }
        __syncthreads();
        bf16x8 pa0 = *reinterpret_cast<const bf16x8*>(pw + ((wh * 2 + 0) * 64 + lane) * 16);
        bf16x8 pa1 = *reinterpret_cast<const bf16x8*>(pw + ((wh * 2 + 1) * 64 + lane) * 16);
#pragma unroll
        for (int n = 0; n < 4; ++n) {
            o[0][n] = __builtin_amdgcn_mfma_f32_16x16x32_bf16(pa0, bt[n], o[0][n], 0, 0, 0);
            o[1][n] = __builtin_amdgcn_mfma_f32_16x16x32_bf16(pa1, bt[n], o[1][n], 0, 0, 0);
        }
        csv = csn;
    }

    // Z reduce + cross-wg combine
#pragma unroll
    for (int hf = 0; hf < 2; ++hf) {
        zacc[hf] += __shfl_xor(zacc[hf], 16);
        zacc[hf] += __shfl_xor(zacc[hf], 32);
    }
    if (lane < 16) {
        zred[wh][0][wg][lane] = zacc[0];
        zred[wh][1][wg][lane] = zacc[1];
    }
    __syncthreads();

    float g_ = gamma[0];
#pragma unroll
    for (int hf = 0; hf < 2; ++hf) {
#pragma unroll
        for (int reg = 0; reg < 4; ++reg) {
            int hq = q * 4 + reg;
            float z = zred[wh][hf][0][hq] + zred[wh][hf][1][hq];
            float sc = g_ / z;
            int h = h_base + wh * 32 + hf * 16 + hq;
#pragma unroll
            for (int n = 0; n < 4; ++n) {
                int w = wg * 64 + n * 16 + r;
                size_t idx = ((size_t)b * H_ + h) * W_ + w;
                out[idx] = fmaf(sc, o[hf][n][reg], x[idx]);
            }
        }
    }
}

// ---------------------------------------------------------------------------
extern "C" void kernel_launch(void* const* d_in, const int* in_sizes, int n_in,
                              void* d_out, int out_size, void* d_ws, size_t ws_size,
                              hipStream_t stream) {
    const float* x     = (const float*)d_in[0];
    const float* w1    = (const float*)d_in[1];
    const float* b1    = (const float*)d_in[2];
    const float* w2    = (const float*)d_in[3];
    const float* b2    = (const float*)d_in[4];
    const float* gamma = (const float*)d_in[5];
    float* out = (float*)d_out;
    (void)b2;

    char* ws = (char*)d_ws;
    const size_t XB_BYTES = (size_t)B_ * H_ * W_ * 2;   // 8 MB
    short* Xbt = (short*)ws;
    short* XTt = (short*)(ws + XB_BYTES);
    float* cs  = (float*)(ws + 2 * XB_BYTES);

    prep<<<B_ * 32, 256, 0, stream>>>(x, b1, w2, Xbt, XTt, cs);
    fused_attn<<<B_ * H_ / 64, 256, 0, stream>>>(x, Xbt, XTt, cs, w1, w2, gamma, out);
}

// Round 8
// 163.935 us; speedup vs baseline: 1.0896x; 1.0896x over previous
//
#include <hip/hip_runtime.h>
#include <hip/hip_bf16.h>

// Sizes fixed by the reference
#define B_ 16
#define H_ 2048
#define W_ 128

using f32x4  = __attribute__((ext_vector_type(4))) float;
using bf16x8 = __attribute__((ext_vector_type(8))) short;

// async global->LDS, 16B per lane. LDS dest is wave-uniform base (HW adds
// lane*16); global src is per-lane.
#define GLOAD_LDS16(g, l) __builtin_amdgcn_global_load_lds( \
    (const __attribute__((address_space(1))) unsigned int*)(g), \
    (__attribute__((address_space(3))) unsigned int*)(l), 16, 0, 0)

__device__ inline short bf16bits(float f) {
    union { __hip_bfloat16 h; short s; } u;
    u.h = __float2bfloat16(f);
    return u.s;
}

// ---------------------------------------------------------------------------
// prep v2: one block (512 thr) per 64 g-rows of one batch.
//  Xbt: fragment-major bf16, chunk ((g/16)*4+k)*64 + q*16 + r holds
//       X[(g/16)*16+r][k*32+q*8+j]  -- written straight from registers
//  XTt: PV B-operand chunks ((kt*8+nt2)*64 + qp*16 + r) per g64-group holding
//       X[g64*64+kt*32+qp*8+j][nt2*16+r] -- via swizzled bf16 LDS tile,
//       gathered with b32 (2 w-cols at once)
//  cs[b][g] = (sum_c b1_c w2_c) * sum_w x[b,g,w]
// ---------------------------------------------------------------------------
__global__ __launch_bounds__(512) void prep(const float* __restrict__ x,
                                            const float* __restrict__ b1,
                                            const float* __restrict__ w2,
                                            short* __restrict__ Xbt,
                                            short* __restrict__ XTt,
                                            float* __restrict__ cs) {
    __shared__ short xs2[8192];   // 64 x 128 bf16, 16B-chunk XOR swizzle
    int b  = blockIdx.x >> 5;
    int g0 = (blockIdx.x & 31) * 64;
    const float* xb = x + ((size_t)b * H_ + g0) * W_;
    short* outb = Xbt + (size_t)b * H_ * W_ + (size_t)g0 * W_;
    short* outt = XTt + (size_t)b * H_ * W_ + (size_t)g0 * W_;
    int t = threadIdx.x;
    float Cc = 0.f;
#pragma unroll
    for (int c = 0; c < 8; ++c) Cc += b1[c] * w2[c];

#pragma unroll
    for (int half = 0; half < 2; ++half) {
        int p = half * 512 + t;
        int row = p >> 4, seg = p & 15;
        const float* src = xb + (size_t)row * W_ + seg * 8;
        float4 v0 = *reinterpret_cast<const float4*>(src);
        float4 v1 = *reinterpret_cast<const float4*>(src + 4);
        bf16x8 v;
        v[0] = bf16bits(v0.x); v[1] = bf16bits(v0.y);
        v[2] = bf16bits(v0.z); v[3] = bf16bits(v0.w);
        v[4] = bf16bits(v1.x); v[5] = bf16bits(v1.y);
        v[6] = bf16bits(v1.z); v[7] = bf16bits(v1.w);
        int chunk = ((row >> 4) * 4 + (seg >> 2)) * 64 + (seg & 3) * 16 + (row & 15);
        *reinterpret_cast<bf16x8*>(outb + (size_t)chunk * 8) = v;
        float s = (v0.x + v0.y + v0.z + v0.w) + (v1.x + v1.y + v1.z + v1.w);
        s += __shfl_xor(s, 1); s += __shfl_xor(s, 2);
        s += __shfl_xor(s, 4); s += __shfl_xor(s, 8);
        if (seg == 0) cs[b * H_ + g0 + row] = Cc * s;
        int c8 = seg ^ ((row >> 3) & 3);
        *reinterpret_cast<bf16x8*>(&xs2[row * 128 + c8 * 8]) = v;
    }
    __syncthreads();
    // gather: thread t produces chunks 2t and 2t+1 (consecutive w cols)
    {
        int r2 = t & 7, qp = (t >> 3) & 3, nt2 = (t >> 5) & 7, kt = t >> 8;
        int w0 = nt2 * 16 + r2 * 2;
        int c8p = (w0 >> 3) ^ qp;
        int gb = kt * 32 + qp * 8;
        bf16x8 lo, hi;
#pragma unroll
        for (int jj = 0; jj < 8; ++jj) {
            unsigned u = *reinterpret_cast<const unsigned*>(
                &xs2[(gb + jj) * 128 + c8p * 8 + (w0 & 7)]);
            lo[jj] = (short)(u & 0xffffu);
            hi[jj] = (short)(u >> 16);
        }
        *reinterpret_cast<bf16x8*>(outt + (size_t)(t * 2) * 8) = lo;
        *reinterpret_cast<bf16x8*>(outt + (size_t)(t * 2 + 1) * 8) = hi;
    }
}

// ---------------------------------------------------------------------------
// Fused: block = 64 h-rows, 8 waves (wave wv: wh=wv>>1 owns 16h, wg=wv&1 owns
// a 16-g half of each 32-g tile). Counted-vmcnt pipeline: staging loads for
// tile t+1 stay in flight across BOTH barriers of body t (never vmcnt(0) in
// the loop). P exchanged via dbuf LDS (lgkmcnt(0)+barrier, no vmem drain).
//  sweep1: per-row min/max of t = A*S + cs[g]
//  sweep2: e = exp2((t-mn)*inv), Z, O = P @ X;  out = gamma*O/Z + x
// ---------------------------------------------------------------------------
__global__ __launch_bounds__(512, 4) void fused_attn(
    const float* __restrict__ x,
    const short* __restrict__ Xbt, const short* __restrict__ XTt,
    const float* __restrict__ cs,
    const float* __restrict__ w1, const float* __restrict__ w2,
    const float* __restrict__ gamma, float* __restrict__ out) {
    __shared__ __align__(16) char stgA[2][8192];   // 32g x 128k bf16 tile
    __shared__ __align__(16) char stgV[2][8192];   // 128w x 32g bf16 tile
    __shared__ __align__(16) char pb[2][4096];     // P: 64h x 32g bf16, dbuf
    __shared__ float red_mn[4][2][16];             // [wh][wg][r]
    __shared__ float red_mx[4][2][16];
    __shared__ float zred[4][2][16];

    float A = 0.f;
#pragma unroll
    for (int c = 0; c < 8; ++c) A += w1[c] * w2[c];

    int tid = threadIdx.x;
    int wv = tid >> 6, lane = tid & 63;
    int wh = wv >> 1, wg = wv & 1;
    int q = lane >> 4, r = lane & 15;

    // XCD swizzle: XCD k gets a contiguous 64-block span = 2 batches
    int bid = blockIdx.x;
    int swz = (bid & 7) * 64 + (bid >> 3);
    int b = swz >> 5, hb = swz & 31;
    int h_base = hb * 64;

    const char* xbt = (const char*)(Xbt + (size_t)b * H_ * W_);
    const char* xtt = (const char*)(XTt + (size_t)b * H_ * W_);
    const float* csb = cs + b * H_;

    // A-fragment: 16h x 128k for this wave's h-group, in regs
    bf16x8 afr[4];
#pragma unroll
    for (int k = 0; k < 4; ++k)
        afr[k] = *reinterpret_cast<const bf16x8*>(
            xbt + ((size_t)(((h_base >> 4) + wh) * 4 + k) * 64 + lane) * 16);

    // ---------------- sweep 1: per-row min / max ----------------
    float mnv = 3.4e38f, mxv = -3.4e38f;
    GLOAD_LDS16(xbt + wv * 1024 + lane * 16, stgA[0] + wv * 1024);
    float4 csv = *reinterpret_cast<const float4*>(csb + wg * 16 + q * 4);
    for (int t = 0; t < 64; ++t) {
        int tn = (t + 1) & 63;
        float4 csn = *reinterpret_cast<const float4*>(csb + tn * 32 + wg * 16 + q * 4);
        GLOAD_LDS16(xbt + (size_t)tn * 8192 + wv * 1024 + lane * 16,
                    stgA[tn & 1] + wv * 1024);
        asm volatile("s_waitcnt vmcnt(2)" ::: "memory");
        __builtin_amdgcn_s_barrier();
        __builtin_amdgcn_sched_barrier(0);
        const char* sa = stgA[t & 1];
        f32x4 s = {0.f, 0.f, 0.f, 0.f};
        __builtin_amdgcn_s_setprio(1);
#pragma unroll
        for (int k = 0; k < 4; ++k) {
            bf16x8 bfr = *reinterpret_cast<const bf16x8*>(sa + ((wg * 4 + k) * 64 + lane) * 16);
            s = __builtin_amdgcn_mfma_f32_16x16x32_bf16(bfr, afr[k], s, 0, 0, 0);
        }
        __builtin_amdgcn_s_setprio(0);
#pragma unroll
        for (int reg = 0; reg < 4; ++reg) {
            float tv = fmaf(A, s[reg], csv[reg]);
            mnv = fminf(mnv, tv); mxv = fmaxf(mxv, tv);
        }
        __builtin_amdgcn_s_barrier();              // WAR guard (no drain)
        __builtin_amdgcn_sched_barrier(0);
        csv = csn;
    }
    mnv = fminf(mnv, __shfl_xor(mnv, 16)); mnv = fminf(mnv, __shfl_xor(mnv, 32));
    mxv = fmaxf(mxv, __shfl_xor(mxv, 16)); mxv = fmaxf(mxv, __shfl_xor(mxv, 32));
    if (lane < 16) { red_mn[wh][wg][lane] = mnv; red_mx[wh][wg][lane] = mxv; }
    __syncthreads();
    const float LOG2E = 1.4426950408889634f;
    float mn = fminf(red_mn[wh][0][r], red_mn[wh][1][r]);
    float mx = fmaxf(red_mx[wh][0][r], red_mx[wh][1][r]);
    float inv = LOG2E / (mx - mn + 1e-8f);
    float c1 = inv, c0v = -mn * inv, A1 = A * inv;

    // ---------------- sweep 2: exp + Z + O = P @ X ----------------
    f32x4 o[4];
#pragma unroll
    for (int i = 0; i < 4; ++i) o[i] = (f32x4){0.f, 0.f, 0.f, 0.f};
    float zacc = 0.f;
    GLOAD_LDS16(xbt + wv * 1024 + lane * 16, stgA[0] + wv * 1024);
    GLOAD_LDS16(xtt + wv * 1024 + lane * 16, stgV[0] + wv * 1024);
    csv = *reinterpret_cast<const float4*>(csb + wg * 16 + q * 4);
    for (int t = 0; t < 64; ++t) {
        int tn = (t + 1) & 63;
        float4 csn = *reinterpret_cast<const float4*>(csb + tn * 32 + wg * 16 + q * 4);
        GLOAD_LDS16(xbt + (size_t)tn * 8192 + wv * 1024 + lane * 16,
                    stgA[tn & 1] + wv * 1024);
        GLOAD_LDS16(xtt + (size_t)tn * 8192 + wv * 1024 + lane * 16,
                    stgV[tn & 1] + wv * 1024);
        asm volatile("s_waitcnt vmcnt(3)" ::: "memory");
        __builtin_amdgcn_s_barrier();
        __builtin_amdgcn_sched_barrier(0);
        const char* sa = stgA[t & 1];
        const char* sv = stgV[t & 1];
        bf16x8 bt[4];
#pragma unroll
        for (int n = 0; n < 4; ++n)
            bt[n] = *reinterpret_cast<const bf16x8*>(sv + ((wg * 4 + n) * 64 + lane) * 16);
        f32x4 s = {0.f, 0.f, 0.f, 0.f};
        __builtin_amdgcn_s_setprio(1);
#pragma unroll
        for (int k = 0; k < 4; ++k) {
            bf16x8 bfr = *reinterpret_cast<const bf16x8*>(sa + ((wg * 4 + k) * 64 + lane) * 16);
            s = __builtin_amdgcn_mfma_f32_16x16x32_bf16(bfr, afr[k], s, 0, 0, 0);
        }
        __builtin_amdgcn_s_setprio(0);
        float e0 = exp2f(fmaf(s[0], A1, fmaf(csv[0], c1, c0v)));
        float e1 = exp2f(fmaf(s[1], A1, fmaf(csv[1], c1, c0v)));
        float e2 = exp2f(fmaf(s[2], A1, fmaf(csv[2], c1, c0v)));
        float e3 = exp2f(fmaf(s[3], A1, fmaf(csv[3], c1, c0v)));
        zacc += (e0 + e1) + (e2 + e3);
        unsigned d0 = (unsigned)(unsigned short)bf16bits(e0) |
                      ((unsigned)(unsigned short)bf16bits(e1) << 16);
        unsigned d1 = (unsigned)(unsigned short)bf16bits(e2) |
                      ((unsigned)(unsigned short)bf16bits(e3) << 16);
        uint2 dd; dd.x = d0; dd.y = d1;
        char* pw = pb[t & 1];
        *reinterpret_cast<uint2*>(
            pw + ((wh * 64 + (wg * 2 + (q >> 1)) * 16 + r) * 16 + (q & 1) * 8)) = dd;
        asm volatile("s_waitcnt lgkmcnt(0)" ::: "memory");
        __builtin_amdgcn_s_barrier();
        __builtin_amdgcn_sched_barrier(0);
        bf16x8 pa = *reinterpret_cast<const bf16x8*>(pw + (wh * 64 + lane) * 16);
        __builtin_amdgcn_s_setprio(1);
#pragma unroll
        for (int n = 0; n < 4; ++n)
            o[n] = __builtin_amdgcn_mfma_f32_16x16x32_bf16(pa, bt[n], o[n], 0, 0, 0);
        __builtin_amdgcn_s_setprio(0);
        csv = csn;
    }

    // Z reduce + cross-wg combine
    zacc += __shfl_xor(zacc, 16); zacc += __shfl_xor(zacc, 32);
    if (lane < 16) zred[wh][wg][lane] = zacc;
    __syncthreads();

    float g_ = gamma[0];
#pragma unroll
    for (int reg = 0; reg < 4; ++reg) {
        int hq = q * 4 + reg;
        float z = zred[wh][0][hq] + zred[wh][1][hq];
        float sc = g_ / z;
        int h = h_base + wh * 16 + hq;
#pragma unroll
        for (int n = 0; n < 4; ++n) {
            int w = wg * 64 + n * 16 + r;
            size_t idx = ((size_t)b * H_ + h) * W_ + w;
            out[idx] = fmaf(sc, o[n][reg], x[idx]);
        }
    }
}

// ---------------------------------------------------------------------------
extern "C" void kernel_launch(void* const* d_in, const int* in_sizes, int n_in,
                              void* d_out, int out_size, void* d_ws, size_t ws_size,
                              hipStream_t stream) {
    const float* x     = (const float*)d_in[0];
    const float* w1    = (const float*)d_in[1];
    const float* b1    = (const float*)d_in[2];
    const float* w2    = (const float*)d_in[3];
    const float* b2    = (const float*)d_in[4];
    const float* gamma = (const float*)d_in[5];
    float* out = (float*)d_out;
    (void)b2;

    char* ws = (char*)d_ws;
    const size_t XB_BYTES = (size_t)B_ * H_ * W_ * 2;   // 8 MB
    short* Xbt = (short*)ws;
    short* XTt = (short*)(ws + XB_BYTES);
    float* cs  = (float*)(ws + 2 * XB_BYTES);

    prep<<<B_ * 32, 512, 0, stream>>>(x, b1, w2, Xbt, XTt, cs);
    fused_attn<<<B_ * H_ / 64, 512, 0, stream>>>(x, Xbt, XTt, cs, w1, w2, gamma, out);
}

// Round 9
// 152.400 us; speedup vs baseline: 1.1721x; 1.0757x over previous
//
#include <hip/hip_runtime.h>
#include <hip/hip_bf16.h>

// Sizes fixed by the reference
#define B_ 16
#define H_ 2048
#define W_ 128

using f32x4  = __attribute__((ext_vector_type(4))) float;
using bf16x8 = __attribute__((ext_vector_type(8))) short;
using bf16x4 = __attribute__((ext_vector_type(4))) short;

// async global->LDS, 16B per lane. LDS dest is wave-uniform base (HW adds
// lane*16); global src is per-lane.
#define GLOAD_LDS16(g, l) __builtin_amdgcn_global_load_lds( \
    (const __attribute__((address_space(1))) unsigned int*)(g), \
    (__attribute__((address_space(3))) unsigned int*)(l), 16, 0, 0)

__device__ inline short bf16bits(float f) {
    union { __hip_bfloat16 h; short s; } u;
    u.h = __float2bfloat16(f);
    return u.s;
}

// ---------------------------------------------------------------------------
// prep: one block (512 thr) per 64 g-rows of one batch.
//  Xbt: S-fragment chunks (1KB): chunk ((g/16)*4+k)*64 + q*16 + r holds
//       X[(g/16)*16+r][k*32+q*8+j] (j 0..7)      [16x16x32 A/B frag]
//  XTt: PV A-operand chunks (512B) per 32g-tile: chunk (gb2*8+n), lane (q,r)
//       holds X[tile*32+gb2*16+q*4+j][n*16+r] (j 0..3)  [16x16x16 A frag]
//  cs[b][g] = (sum_c b1_c w2_c) * sum_w x[b,g,w]
// ---------------------------------------------------------------------------
__global__ __launch_bounds__(512) void prep(const float* __restrict__ x,
                                            const float* __restrict__ b1,
                                            const float* __restrict__ w2,
                                            short* __restrict__ Xbt,
                                            char* __restrict__ XTt,
                                            float* __restrict__ cs) {
    __shared__ short xs2[8192];   // 64 x 128 bf16, 16B-chunk XOR swizzle
    int b  = blockIdx.x >> 5;
    int g0 = (blockIdx.x & 31) * 64;
    const float* xb = x + ((size_t)b * H_ + g0) * W_;
    short* outb = Xbt + (size_t)b * H_ * W_ + (size_t)g0 * W_;
    char* outt = XTt + (size_t)b * H_ * W_ * 2 + (size_t)g0 * W_ * 2;
    int t = threadIdx.x;
    float Cc = 0.f;
#pragma unroll
    for (int c = 0; c < 8; ++c) Cc += b1[c] * w2[c];

#pragma unroll
    for (int half = 0; half < 2; ++half) {
        int p = half * 512 + t;
        int row = p >> 4, seg = p & 15;
        const float* src = xb + (size_t)row * W_ + seg * 8;
        float4 v0 = *reinterpret_cast<const float4*>(src);
        float4 v1 = *reinterpret_cast<const float4*>(src + 4);
        bf16x8 v;
        v[0] = bf16bits(v0.x); v[1] = bf16bits(v0.y);
        v[2] = bf16bits(v0.z); v[3] = bf16bits(v0.w);
        v[4] = bf16bits(v1.x); v[5] = bf16bits(v1.y);
        v[6] = bf16bits(v1.z); v[7] = bf16bits(v1.w);
        int chunk = ((row >> 4) * 4 + (seg >> 2)) * 64 + (seg & 3) * 16 + (row & 15);
        *reinterpret_cast<bf16x8*>(outb + (size_t)chunk * 8) = v;
        float s = (v0.x + v0.y + v0.z + v0.w) + (v1.x + v1.y + v1.z + v1.w);
        s += __shfl_xor(s, 1); s += __shfl_xor(s, 2);
        s += __shfl_xor(s, 4); s += __shfl_xor(s, 8);
        if (seg == 0) cs[b * H_ + g0 + row] = Cc * s;
        int c8 = seg ^ ((row >> 3) & 3);
        *reinterpret_cast<bf16x8*>(&xs2[row * 128 + c8 * 8]) = v;
    }
    __syncthreads();
    // XTt gather: 1024 items, 2 per thread; item -> 16B (lanes rr*2, rr*2+1)
#pragma unroll
    for (int it2 = 0; it2 < 2; ++it2) {
        int i = it2 * 512 + t;
        int rr = i & 7, q = (i >> 3) & 3, n = (i >> 5) & 7, gq = i >> 8; // gq 0..3
        int w0 = n * 16 + rr * 2;
        int rs = (gq * 2 + (q >> 1)) & 3;
        int c8p = (w0 >> 3) ^ rs;
        int gbase = gq * 16 + q * 4;
        unsigned u0 = *reinterpret_cast<const unsigned*>(&xs2[(gbase + 0) * 128 + c8p * 8 + (w0 & 7)]);
        unsigned u1 = *reinterpret_cast<const unsigned*>(&xs2[(gbase + 1) * 128 + c8p * 8 + (w0 & 7)]);
        unsigned u2 = *reinterpret_cast<const unsigned*>(&xs2[(gbase + 2) * 128 + c8p * 8 + (w0 & 7)]);
        unsigned u3 = *reinterpret_cast<const unsigned*>(&xs2[(gbase + 3) * 128 + c8p * 8 + (w0 & 7)]);
        uint4 outv;
        outv.x = (u0 & 0xffffu) | (u1 << 16);                 // lane rr*2, j0..1
        outv.y = (u2 & 0xffffu) | (u3 << 16);                 // lane rr*2, j2..3
        outv.z = (u0 >> 16) | (u1 & 0xffff0000u);             // lane rr*2+1
        outv.w = (u2 >> 16) | (u3 & 0xffff0000u);
        int tloc = gq >> 1, gb2 = gq & 1;
        size_t addr = (size_t)tloc * 8192 + ((gb2 * 8 + n) * 512) + (q * 16 + rr * 2) * 8;
        *reinterpret_cast<uint4*>(outt + addr) = outv;
    }
}

// ---------------------------------------------------------------------------
// Fused: block = 64 h-rows, 8 waves (wh=wv>>1: 16h group; wg=wv&1: 16-g half
// of each 32-g tile). Triple-buffered staging -> ONE barrier per body;
// counted vmcnt (sweep1: 1, sweep2: 2; last iter drains 0). P self-consumed:
// swapped S-MFMA D-frag == B-frag of v_mfma_f32_16x16x16_bf16 -> PV needs no
// LDS P exchange. O^T partials (per wg) combined once in epilogue via LDS.
// ---------------------------------------------------------------------------
__global__ __launch_bounds__(512, 4) void fused_attn(
    const float* __restrict__ x,
    const short* __restrict__ Xbt, const char* __restrict__ XTt,
    const float* __restrict__ cs,
    const float* __restrict__ w1, const float* __restrict__ w2,
    const float* __restrict__ gamma, float* __restrict__ out) {
    __shared__ __align__(16) char smem[58880];
    char* stgA = smem;                 // 3 x 8192: S-frag tiles (32g x 128k)
    char* stgV = smem + 24576;         // 3 x 8192: PV A-frag tiles
    float* csl = (float*)(smem + 49152);       // 2048 f32
    float* redmn = (float*)(smem + 57344);     // [4][2][16]
    float* redmx = (float*)(smem + 57856);
    float* zred  = (float*)(smem + 58368);

    float A = 0.f;
#pragma unroll
    for (int c = 0; c < 8; ++c) A += w1[c] * w2[c];

    int tid = threadIdx.x;
    int wv = tid >> 6, lane = tid & 63;
    int wh = wv >> 1, wg = wv & 1;
    int q = lane >> 4, r = lane & 15;

    // XCD swizzle: XCD k gets a contiguous 64-block span = 2 batches
    int bid = blockIdx.x;
    int swz = (bid & 7) * 64 + (bid >> 3);
    int b = swz >> 5, hb = swz & 31;
    int h_base = hb * 64;

    const char* xbt = (const char*)(Xbt + (size_t)b * H_ * W_);
    const char* xtt = XTt + (size_t)b * H_ * W_ * 2;
    const float* csb = cs + b * H_;

    // prologue: afr, cs -> LDS, stage tile 0 (A)
    bf16x8 afr[4];
#pragma unroll
    for (int k = 0; k < 4; ++k)
        afr[k] = *reinterpret_cast<const bf16x8*>(
            xbt + ((size_t)(((h_base >> 4) + wh) * 4 + k) * 64 + lane) * 16);
    {
        float4 cv = *reinterpret_cast<const float4*>(csb + tid * 4);
        *reinterpret_cast<float4*>(csl + tid * 4) = cv;
    }
    GLOAD_LDS16(xbt + wv * 1024 + lane * 16, stgA + wv * 1024);
    __syncthreads();

    // ---------------- sweep 1: per-row min / max ----------------
    float mnv = 3.4e38f, mxv = -3.4e38f;
    int cur = 0;
    for (int t = 0; t < 64; ++t) {
        int nxt = (cur == 2) ? 0 : cur + 1;
        if (t < 63) {
            GLOAD_LDS16(xbt + (size_t)(t + 1) * 8192 + wv * 1024 + lane * 16,
                        stgA + nxt * 8192 + wv * 1024);
            asm volatile("s_waitcnt vmcnt(1)" ::: "memory");
        } else {
            asm volatile("s_waitcnt vmcnt(0)" ::: "memory");
        }
        __builtin_amdgcn_s_barrier();
        __builtin_amdgcn_sched_barrier(0);
        float4 csq = *reinterpret_cast<const float4*>(csl + t * 32 + wg * 16 + q * 4);
        const char* sa = stgA + cur * 8192;
        f32x4 s = {0.f, 0.f, 0.f, 0.f};
        __builtin_amdgcn_s_setprio(1);
#pragma unroll
        for (int k = 0; k < 4; ++k) {
            bf16x8 bfr = *reinterpret_cast<const bf16x8*>(sa + ((wg * 4 + k) * 64 + lane) * 16);
            s = __builtin_amdgcn_mfma_f32_16x16x32_bf16(bfr, afr[k], s, 0, 0, 0);
        }
        __builtin_amdgcn_s_setprio(0);
#pragma unroll
        for (int reg = 0; reg < 4; ++reg) {
            float tv = fmaf(A, s[reg], csq[reg]);
            mnv = fminf(mnv, tv); mxv = fmaxf(mxv, tv);
        }
        cur = nxt;
    }
    mnv = fminf(mnv, __shfl_xor(mnv, 16)); mnv = fminf(mnv, __shfl_xor(mnv, 32));
    mxv = fmaxf(mxv, __shfl_xor(mxv, 16)); mxv = fmaxf(mxv, __shfl_xor(mxv, 32));
    if (lane < 16) {
        redmn[(wh * 2 + wg) * 16 + lane] = mnv;
        redmx[(wh * 2 + wg) * 16 + lane] = mxv;
    }
    __syncthreads();
    const float LOG2E = 1.4426950408889634f;
    float mn = fminf(redmn[(wh * 2 + 0) * 16 + r], redmn[(wh * 2 + 1) * 16 + r]);
    float mx = fmaxf(redmx[(wh * 2 + 0) * 16 + r], redmx[(wh * 2 + 1) * 16 + r]);
    float inv = LOG2E / (mx - mn + 1e-8f);
    float c1 = inv, c0v = -mn * inv, A1 = A * inv;

    // ---------------- sweep 2: exp + Z + O^T = X^T P^T ----------------
    f32x4 o[8];
#pragma unroll
    for (int i = 0; i < 8; ++i) o[i] = (f32x4){0.f, 0.f, 0.f, 0.f};
    float zacc = 0.f;
    GLOAD_LDS16(xbt + wv * 1024 + lane * 16, stgA + wv * 1024);
    GLOAD_LDS16(xtt + wv * 1024 + lane * 16, stgV + wv * 1024);
    cur = 0;
    for (int t = 0; t < 64; ++t) {
        int nxt = (cur == 2) ? 0 : cur + 1;
        if (t < 63) {
            GLOAD_LDS16(xbt + (size_t)(t + 1) * 8192 + wv * 1024 + lane * 16,
                        stgA + nxt * 8192 + wv * 1024);
            GLOAD_LDS16(xtt + (size_t)(t + 1) * 8192 + wv * 1024 + lane * 16,
                        stgV + nxt * 8192 + wv * 1024);
            asm volatile("s_waitcnt vmcnt(2)" ::: "memory");
        } else {
            asm volatile("s_waitcnt vmcnt(0)" ::: "memory");
        }
        __builtin_amdgcn_s_barrier();
        __builtin_amdgcn_sched_barrier(0);
        float4 csq = *reinterpret_cast<const float4*>(csl + t * 32 + wg * 16 + q * 4);
        const char* sa = stgA + cur * 8192;
        const char* sv = stgV + cur * 8192;
        f32x4 s = {0.f, 0.f, 0.f, 0.f};
        __builtin_amdgcn_s_setprio(1);
#pragma unroll
        for (int k = 0; k < 4; ++k) {
            bf16x8 bfr = *reinterpret_cast<const bf16x8*>(sa + ((wg * 4 + k) * 64 + lane) * 16);
            s = __builtin_amdgcn_mfma_f32_16x16x32_bf16(bfr, afr[k], s, 0, 0, 0);
        }
        __builtin_amdgcn_s_setprio(0);
        float e0 = exp2f(fmaf(s[0], A1, fmaf(csq[0], c1, c0v)));
        float e1 = exp2f(fmaf(s[1], A1, fmaf(csq[1], c1, c0v)));
        float e2 = exp2f(fmaf(s[2], A1, fmaf(csq[2], c1, c0v)));
        float e3 = exp2f(fmaf(s[3], A1, fmaf(csq[3], c1, c0v)));
        zacc += (e0 + e1) + (e2 + e3);
        bf16x4 pf;
        pf[0] = bf16bits(e0); pf[1] = bf16bits(e1);
        pf[2] = bf16bits(e2); pf[3] = bf16bits(e3);
        // PV: O^T[w][h] += mfma16(X^T-frag, P-frag); A-frag chunks 512B
        __builtin_amdgcn_s_setprio(1);
#pragma unroll
        for (int n = 0; n < 8; ++n) {
            bf16x4 av = *reinterpret_cast<const bf16x4*>(
                sv + (wg * 8 + n) * 512 + lane * 8);
            asm("v_mfma_f32_16x16x16_bf16 %0, %1, %2, %0"
                : "+v"(o[n]) : "v"(av), "v"(pf));
        }
        __builtin_amdgcn_s_setprio(0);
        cur = nxt;
    }

    // Z reduce + cross-wg combine
    zacc += __shfl_xor(zacc, 16); zacc += __shfl_xor(zacc, 32);
    if (lane < 16) zred[(wh * 2 + wg) * 16 + lane] = zacc;
    __syncthreads();   // also: staging buffers dead -> reuse as ocomb

    // O combine: wg=0 writes partials, wg=1 adds and stores final out
    float* ocw = (float*)smem + wh * 2112;   // [16h][132w] padded
    if (wg == 0) {
#pragma unroll
        for (int n = 0; n < 8; ++n)
            *reinterpret_cast<float4*>(ocw + r * 132 + n * 16 + q * 4) =
                (float4){o[n][0], o[n][1], o[n][2], o[n][3]};
    }
    __syncthreads();
    if (wg == 1) {
        float z = zred[(wh * 2 + 0) * 16 + r] + zred[(wh * 2 + 1) * 16 + r];
        float sc = gamma[0] / z;
        int h = h_base + wh * 16 + r;
        const float* xrow = x + ((size_t)b * H_ + h) * W_;
        float* orow = out + ((size_t)b * H_ + h) * W_;
#pragma unroll
        for (int n = 0; n < 8; ++n) {
            float4 p0 = *reinterpret_cast<const float4*>(ocw + r * 132 + n * 16 + q * 4);
            float4 xv = *reinterpret_cast<const float4*>(xrow + n * 16 + q * 4);
            float4 res;
            res.x = fmaf(sc, p0.x + o[n][0], xv.x);
            res.y = fmaf(sc, p0.y + o[n][1], xv.y);
            res.z = fmaf(sc, p0.z + o[n][2], xv.z);
            res.w = fmaf(sc, p0.w + o[n][3], xv.w);
            *reinterpret_cast<float4*>(orow + n * 16 + q * 4) = res;
        }
    }
}

// ---------------------------------------------------------------------------
extern "C" void kernel_launch(void* const* d_in, const int* in_sizes, int n_in,
                              void* d_out, int out_size, void* d_ws, size_t ws_size,
                              hipStream_t stream) {
    const float* x     = (const float*)d_in[0];
    const float* w1    = (const float*)d_in[1];
    const float* b1    = (const float*)d_in[2];
    const float* w2    = (const float*)d_in[3];
    const float* b2    = (const float*)d_in[4];
    const float* gamma = (const float*)d_in[5];
    float* out = (float*)d_out;
    (void)b2;

    char* ws = (char*)d_ws;
    const size_t XB_BYTES = (size_t)B_ * H_ * W_ * 2;   // 8 MB
    short* Xbt = (short*)ws;
    char*  XTt = ws + XB_BYTES;
    float* cs  = (float*)(ws + 2 * XB_BYTES);

    prep<<<B_ * 32, 512, 0, stream>>>(x, b1, w2, Xbt, XTt, cs);
    fused_attn<<<B_ * H_ / 64, 512, 0, stream>>>(x, Xbt, XTt, cs, w1, w2, gamma, out);
}